// Round 1
// baseline (5447.676 us; speedup 1.0000x reference)
//
#include <hip/hip_runtime.h>
#include <math.h>

// Problem constants
#define RR 16384        // B*N rows
#define DD 512          // feature dim
#define CC 4096         // codebook size
#define QQ 4            // num quantizers
#define QOUT_SZ (RR*DD)           // 8388608
#define IDX_OFF QOUT_SZ
#define LOSS_OFF (QOUT_SZ + RR*QQ)
#define LOSS_COEF (1.25f / 8388608.0f)

// Workspace layout (float offsets)
#define WS_RESID 0                         // 8388608
#define WS_CBN   (RR*DD)                   // +2097152 -> 10485760
#define WS_RINV  (WS_CBN + CC*DD)          // +16384
#define WS_RNRM  (WS_RINV + RR)            // +16384
#define WS_PVAL  (WS_RNRM + RR)            // +32768 (RR*2)
#define WS_PIDX  (WS_PVAL + 2*RR)          // +32768
#define WS_LOSS  (WS_PIDX + 2*RR)          // +4

__device__ __forceinline__ float waveSum(float v) {
#pragma unroll
    for (int m = 1; m < 64; m <<= 1) v += __shfl_xor(v, m, 64);
    return v;
}

// ---------------- init: resid = x, qout = 0, loss = 0 ----------------
__global__ void initK(const float* __restrict__ x, float* __restrict__ resid,
                      float* __restrict__ dout, float* __restrict__ loss) {
    int i = blockIdx.x * blockDim.x + threadIdx.x;
    int stride = gridDim.x * blockDim.x;
    for (; i < QOUT_SZ; i += stride) { resid[i] = x[i]; dout[i] = 0.0f; }
    if (blockIdx.x == 0 && threadIdx.x < QQ) loss[threadIdx.x] = 0.0f;
}

// ---------------- implicit_cb = codebooks[q] @ weights[q]^T ----------------
// out[c][d] = sum_k A[c][k]*W[d][k].  64x64 tiles, BK=32, 4x4 thread tiles.
__global__ __launch_bounds__(256) void gemmCbK(const float* __restrict__ A,
                                               const float* __restrict__ W,
                                               float* __restrict__ out) {
    __shared__ float As[32][64];
    __shared__ float Bs[32][64];
    int t = threadIdx.x;
    int tx = t & 15, ty = t >> 4;
    int cBase = blockIdx.x * 64;
    int dBase = blockIdx.y * 64;
    int f = t & 7;        // which float4 along k (8*4=32)
    int mq = t >> 3;      // row 0..31 (+32 on pass 2)
    float acc[4][4] = {};
    for (int k0 = 0; k0 < DD; k0 += 32) {
        __syncthreads();
#pragma unroll
        for (int p = 0; p < 2; ++p) {
            int m = mq + p * 32;
            float4 av = *(const float4*)&A[(size_t)(cBase + m) * DD + k0 + f * 4];
            As[f*4+0][m] = av.x; As[f*4+1][m] = av.y; As[f*4+2][m] = av.z; As[f*4+3][m] = av.w;
            float4 wv = *(const float4*)&W[(size_t)(dBase + m) * DD + k0 + f * 4];
            Bs[f*4+0][m] = wv.x; Bs[f*4+1][m] = wv.y; Bs[f*4+2][m] = wv.z; Bs[f*4+3][m] = wv.w;
        }
        __syncthreads();
#pragma unroll
        for (int kk = 0; kk < 32; ++kk) {
            float4 a4 = *(const float4*)&As[kk][ty * 4];
            float4 b4 = *(const float4*)&Bs[kk][tx * 4];
            float a[4] = {a4.x, a4.y, a4.z, a4.w};
            float b[4] = {b4.x, b4.y, b4.z, b4.w};
#pragma unroll
            for (int i = 0; i < 4; ++i)
#pragma unroll
                for (int j = 0; j < 4; ++j) acc[i][j] += a[i] * b[j];
        }
    }
#pragma unroll
    for (int i = 0; i < 4; ++i) {
        float4 v = make_float4(acc[i][0], acc[i][1], acc[i][2], acc[i][3]);
        *(float4*)&out[(size_t)(cBase + ty * 4 + i) * DD + dBase + tx * 4] = v;
    }
}

// ---------------- normalize rows of cbn in place (division, ref fidelity) -----
__global__ void rowNormInplaceK(float* __restrict__ buf) {
    int wave = threadIdx.x >> 6, lane = threadIdx.x & 63;
    int row = blockIdx.x * 4 + wave;
    float* p = buf + (size_t)row * DD;
    float4 v0 = *(float4*)&p[lane * 8];
    float4 v1 = *(float4*)&p[lane * 8 + 4];
    float ss = v0.x*v0.x + v0.y*v0.y + v0.z*v0.z + v0.w*v0.w
             + v1.x*v1.x + v1.y*v1.y + v1.z*v1.z + v1.w*v1.w;
    ss = waveSum(ss);
    float nrm = fmaxf(sqrtf(ss), 1e-12f);
    v0.x /= nrm; v0.y /= nrm; v0.z /= nrm; v0.w /= nrm;
    v1.x /= nrm; v1.y /= nrm; v1.z /= nrm; v1.w /= nrm;
    *(float4*)&p[lane * 8] = v0;
    *(float4*)&p[lane * 8 + 4] = v1;
}

// ---------------- per-row norms of residual ----------------
__global__ void rowInvNormK(const float* __restrict__ resid,
                            float* __restrict__ rinv, float* __restrict__ rnrm) {
    int wave = threadIdx.x >> 6, lane = threadIdx.x & 63;
    int row = blockIdx.x * 4 + wave;
    const float* p = resid + (size_t)row * DD;
    float4 v0 = *(const float4*)&p[lane * 8];
    float4 v1 = *(const float4*)&p[lane * 8 + 4];
    float ss = v0.x*v0.x + v0.y*v0.y + v0.z*v0.z + v0.w*v0.w
             + v1.x*v1.x + v1.y*v1.y + v1.z*v1.z + v1.w*v1.w;
    ss = waveSum(ss);
    float nrm = fmaxf(sqrtf(ss), 1e-12f);
    if (lane == 0) { rinv[row] = 1.0f / nrm; rnrm[row] = nrm; }
}

// ---------------- fused sim GEMM + argmax ----------------
// 128 rows x 2048 cols per block (c split in 2 halves), BK=16, 8x8 thread tiles.
__global__ __launch_bounds__(256) void simArgmaxK(const float* __restrict__ resid,
                                                  const float* __restrict__ rinv,
                                                  const float* __restrict__ cbn,
                                                  float* __restrict__ pvals,
                                                  int* __restrict__ pidx) {
    __shared__ float As[16][128];
    __shared__ float Bs[16][128];
    int t = threadIdx.x;
    int tx = t & 15, ty = t >> 4;
    int rowBase = blockIdx.x * 128;
    int ch = blockIdx.y;               // which c half
    int cBase = ch * (CC / 2);
    int ml = t >> 2;                   // 0..63
    int kq = (t & 3) * 4;              // 0,4,8,12
    float s0 = rinv[rowBase + ml];
    float s1 = rinv[rowBase + ml + 64];
    float best[8]; int bidx[8];
#pragma unroll
    for (int i = 0; i < 8; ++i) { best[i] = -3e38f; bidx[i] = 0; }

    for (int ct = 0; ct < CC / 2; ct += 128) {
        float acc[8][8] = {};
        for (int k0 = 0; k0 < DD; k0 += 16) {
            __syncthreads();
            {
                float4 av = *(const float4*)&resid[(size_t)(rowBase + ml) * DD + k0 + kq];
                As[kq+0][ml] = av.x * s0; As[kq+1][ml] = av.y * s0;
                As[kq+2][ml] = av.z * s0; As[kq+3][ml] = av.w * s0;
                float4 av2 = *(const float4*)&resid[(size_t)(rowBase + ml + 64) * DD + k0 + kq];
                As[kq+0][ml+64] = av2.x * s1; As[kq+1][ml+64] = av2.y * s1;
                As[kq+2][ml+64] = av2.z * s1; As[kq+3][ml+64] = av2.w * s1;
                float4 bv = *(const float4*)&cbn[(size_t)(cBase + ct + ml) * DD + k0 + kq];
                Bs[kq+0][ml] = bv.x; Bs[kq+1][ml] = bv.y;
                Bs[kq+2][ml] = bv.z; Bs[kq+3][ml] = bv.w;
                float4 bv2 = *(const float4*)&cbn[(size_t)(cBase + ct + ml + 64) * DD + k0 + kq];
                Bs[kq+0][ml+64] = bv2.x; Bs[kq+1][ml+64] = bv2.y;
                Bs[kq+2][ml+64] = bv2.z; Bs[kq+3][ml+64] = bv2.w;
            }
            __syncthreads();
#pragma unroll
            for (int kk = 0; kk < 16; ++kk) {
                float4 a0 = *(const float4*)&As[kk][ty * 8];
                float4 a1 = *(const float4*)&As[kk][ty * 8 + 4];
                float4 b0 = *(const float4*)&Bs[kk][tx * 8];
                float4 b1 = *(const float4*)&Bs[kk][tx * 8 + 4];
                float a[8] = {a0.x,a0.y,a0.z,a0.w,a1.x,a1.y,a1.z,a1.w};
                float b[8] = {b0.x,b0.y,b0.z,b0.w,b1.x,b1.y,b1.z,b1.w};
#pragma unroll
                for (int i = 0; i < 8; ++i)
#pragma unroll
                    for (int j = 0; j < 8; ++j) acc[i][j] += a[i] * b[j];
            }
        }
        // per-row argmax over this 128-col tile (first-max tie-break)
#pragma unroll
        for (int i = 0; i < 8; ++i) {
            float v = acc[i][0];
            int ci = cBase + ct + tx * 8;
#pragma unroll
            for (int j = 1; j < 8; ++j) {
                if (acc[i][j] > v) { v = acc[i][j]; ci = cBase + ct + tx * 8 + j; }
            }
#pragma unroll
            for (int m = 1; m < 16; m <<= 1) {
                float ov = __shfl_xor(v, m, 64);
                int oc = __shfl_xor(ci, m, 64);
                if (ov > v || (ov == v && oc < ci)) { v = ov; ci = oc; }
            }
            if (v > best[i] || (v == best[i] && ci < bidx[i])) { best[i] = v; bidx[i] = ci; }
        }
    }
    if (tx == 0) {
#pragma unroll
        for (int i = 0; i < 8; ++i) {
            int row = rowBase + ty * 8 + i;
            pvals[row * 2 + ch] = best[i];
            pidx[row * 2 + ch] = bidx[i];
        }
    }
}

// ---------------- finalize: merge halves, rotation, residual/qout/loss --------
__global__ void finalizeK(float* __restrict__ resid,
                          const float* __restrict__ rnrm,
                          const float* __restrict__ cbn,
                          const float* __restrict__ pvals,
                          const int* __restrict__ pidx,
                          float* __restrict__ dout,
                          float* __restrict__ loss, int q) {
    int wave = threadIdx.x >> 6, lane = threadIdx.x & 63;
    int row = blockIdx.x * 4 + wave;
    float* xr = resid + (size_t)row * DD;
    float nrm = rnrm[row];
    float4 a0 = *(float4*)&xr[lane * 8];
    float4 a1 = *(float4*)&xr[lane * 8 + 4];
    float orig[8] = {a0.x,a0.y,a0.z,a0.w,a1.x,a1.y,a1.z,a1.w};
    float x[8];
#pragma unroll
    for (int j = 0; j < 8; ++j) x[j] = orig[j] / nrm;   // x_n, division per ref

    float v0 = pvals[row * 2], v1 = pvals[row * 2 + 1];
    int idx = (v0 >= v1) ? pidx[row * 2] : pidx[row * 2 + 1];

    const float* qp = cbn + (size_t)idx * DD;
    float4 q0 = *(const float4*)&qp[lane * 8];
    float4 q1 = *(const float4*)&qp[lane * 8 + 4];
    float qv[8] = {q0.x,q0.y,q0.z,q0.w,q1.x,q1.y,q1.z,q1.w};

    float ns2 = 0.f, nt2 = 0.f, lrow = 0.f;
#pragma unroll
    for (int j = 0; j < 8; ++j) {
        ns2 += x[j] * x[j];
        nt2 += qv[j] * qv[j];
        float d = x[j] - qv[j];
        lrow += d * d;
    }
    ns2 = waveSum(ns2); nt2 = waveSum(nt2); lrow = waveSum(lrow);
    float ns = sqrtf(ns2), nt = sqrtf(nt2);

    float u[8], qn[8], w[8];
    float nw2 = 0.f;
#pragma unroll
    for (int j = 0; j < 8; ++j) {
        u[j] = x[j] / ns;
        qn[j] = qv[j] / nt;
        w[j] = u[j] + qn[j];
        nw2 += w[j] * w[j];
    }
    nw2 = waveSum(nw2);
    float nw = fmaxf(sqrtf(nw2), 1e-12f);
    float dew = 0.f, deu = 0.f;
#pragma unroll
    for (int j = 0; j < 8; ++j) {
        w[j] = w[j] / nw;
        dew += x[j] * w[j];
        deu += x[j] * u[j];
    }
    dew = waveSum(dew); deu = waveSum(deu);
    float scale = nt / ns;

    float r[8];
#pragma unroll
    for (int j = 0; j < 8; ++j)
        r[j] = (x[j] - 2.0f * dew * w[j] + 2.0f * deu * qn[j]) * scale;

    // residual -= r ; qout += r
    a0.x = orig[0]-r[0]; a0.y = orig[1]-r[1]; a0.z = orig[2]-r[2]; a0.w = orig[3]-r[3];
    a1.x = orig[4]-r[4]; a1.y = orig[5]-r[5]; a1.z = orig[6]-r[6]; a1.w = orig[7]-r[7];
    *(float4*)&xr[lane * 8] = a0;
    *(float4*)&xr[lane * 8 + 4] = a1;

    float* op = dout + (size_t)row * DD;
    float4 o0 = *(float4*)&op[lane * 8];
    float4 o1 = *(float4*)&op[lane * 8 + 4];
    o0.x += r[0]; o0.y += r[1]; o0.z += r[2]; o0.w += r[3];
    o1.x += r[4]; o1.y += r[5]; o1.z += r[6]; o1.w += r[7];
    *(float4*)&op[lane * 8] = o0;
    *(float4*)&op[lane * 8 + 4] = o1;

    if (lane == 0) {
        dout[IDX_OFF + row * 4 + q] = (float)idx;
        atomicAdd(loss + q, lrow * LOSS_COEF);
    }
}

__global__ void lossWriteK(const float* __restrict__ loss, float* __restrict__ dout) {
    if (threadIdx.x < QQ) dout[LOSS_OFF + threadIdx.x] = loss[threadIdx.x];
}

extern "C" void kernel_launch(void* const* d_in, const int* in_sizes, int n_in,
                              void* d_out, int out_size, void* d_ws, size_t ws_size,
                              hipStream_t stream) {
    const float* x = (const float*)d_in[0];
    const float* codebooks = (const float*)d_in[1];
    const float* weights = (const float*)d_in[2];
    float* dout = (float*)d_out;
    float* w = (float*)d_ws;

    float* resid = w + WS_RESID;
    float* cbn   = w + WS_CBN;
    float* rinv  = w + WS_RINV;
    float* rnrm  = w + WS_RNRM;
    float* pvals = w + WS_PVAL;
    int*   pidx  = (int*)(w + WS_PIDX);
    float* loss  = w + WS_LOSS;

    initK<<<4096, 256, 0, stream>>>(x, resid, dout, loss);

    for (int q = 0; q < QQ; ++q) {
        gemmCbK<<<dim3(CC / 64, DD / 64), 256, 0, stream>>>(
            codebooks + (size_t)q * CC * DD, weights + (size_t)q * DD * DD, cbn);
        rowNormInplaceK<<<CC / 4, 256, 0, stream>>>(cbn);
        rowInvNormK<<<RR / 4, 256, 0, stream>>>(resid, rinv, rnrm);
        simArgmaxK<<<dim3(RR / 128, 2), 256, 0, stream>>>(resid, rinv, cbn, pvals, pidx);
        finalizeK<<<RR / 4, 256, 0, stream>>>(resid, rnrm, cbn, pvals, pidx, dout, loss, q);
    }
    lossWriteK<<<1, 64, 0, stream>>>(loss, dout);
}

// Round 2
// 4447.918 us; speedup vs baseline: 1.2248x; 1.2248x over previous
//
#include <hip/hip_runtime.h>
#include <math.h>

// Problem constants
#define RR 16384        // B*N rows
#define DD 512          // feature dim
#define CC 4096         // codebook size
#define QQ 4            // num quantizers
#define CSPLIT 8
#define CCHUNK (CC / CSPLIT)      // 512
#define QOUT_SZ (RR*DD)           // 8388608
#define IDX_OFF QOUT_SZ
#define LOSS_OFF (QOUT_SZ + RR*QQ)
#define LOSS_COEF (1.25f / 8388608.0f)

// Workspace layout (float offsets)
#define WS_RESID 0                         // 8388608
#define WS_CBN   (RR*DD)                   // +2097152
#define WS_RINV  (WS_CBN + CC*DD)          // +16384
#define WS_RNRM  (WS_RINV + RR)            // +16384
#define WS_PVAL  (WS_RNRM + RR)            // +8*RR
#define WS_PIDX  (WS_PVAL + CSPLIT*RR)     // +8*RR
#define WS_LOSS  (WS_PIDX + CSPLIT*RR)     // +4

__device__ __forceinline__ float waveSum(float v) {
#pragma unroll
    for (int m = 1; m < 64; m <<= 1) v += __shfl_xor(v, m, 64);
    return v;
}

// ---------------- init: resid = x, qout = 0, loss = 0 ----------------
__global__ void initK(const float* __restrict__ x, float* __restrict__ resid,
                      float* __restrict__ dout, float* __restrict__ loss) {
    int i = blockIdx.x * blockDim.x + threadIdx.x;
    int stride = gridDim.x * blockDim.x;
    for (; i < QOUT_SZ; i += stride) { resid[i] = x[i]; dout[i] = 0.0f; }
    if (blockIdx.x == 0 && threadIdx.x < QQ) loss[threadIdx.x] = 0.0f;
}

// ---------------- implicit_cb = codebooks[q] @ weights[q]^T ----------------
// out[c][d] = sum_k A[c][k]*W[d][k].  64x64 tiles, BK=32, 4x4 thread tiles.
__global__ __launch_bounds__(256) void gemmCbK(const float* __restrict__ A,
                                               const float* __restrict__ W,
                                               float* __restrict__ out) {
    __shared__ float As[32][64];
    __shared__ float Bs[32][64];
    int t = threadIdx.x;
    int tx = t & 15, ty = t >> 4;
    int cBase = blockIdx.x * 64;
    int dBase = blockIdx.y * 64;
    int f = t & 7;        // which float4 along k (8*4=32)
    int mq = t >> 3;      // row 0..31 (+32 on pass 2)
    float acc[4][4] = {};
    for (int k0 = 0; k0 < DD; k0 += 32) {
        __syncthreads();
#pragma unroll
        for (int p = 0; p < 2; ++p) {
            int m = mq + p * 32;
            float4 av = *(const float4*)&A[(size_t)(cBase + m) * DD + k0 + f * 4];
            As[f*4+0][m] = av.x; As[f*4+1][m] = av.y; As[f*4+2][m] = av.z; As[f*4+3][m] = av.w;
            float4 wv = *(const float4*)&W[(size_t)(dBase + m) * DD + k0 + f * 4];
            Bs[f*4+0][m] = wv.x; Bs[f*4+1][m] = wv.y; Bs[f*4+2][m] = wv.z; Bs[f*4+3][m] = wv.w;
        }
        __syncthreads();
#pragma unroll
        for (int kk = 0; kk < 32; ++kk) {
            float4 a4 = *(const float4*)&As[kk][ty * 4];
            float4 b4 = *(const float4*)&Bs[kk][tx * 4];
            float a[4] = {a4.x, a4.y, a4.z, a4.w};
            float b[4] = {b4.x, b4.y, b4.z, b4.w};
#pragma unroll
            for (int i = 0; i < 4; ++i)
#pragma unroll
                for (int j = 0; j < 4; ++j) acc[i][j] += a[i] * b[j];
        }
    }
#pragma unroll
    for (int i = 0; i < 4; ++i) {
        float4 v = make_float4(acc[i][0], acc[i][1], acc[i][2], acc[i][3]);
        *(float4*)&out[(size_t)(cBase + ty * 4 + i) * DD + dBase + tx * 4] = v;
    }
}

// ---------------- normalize rows of cbn in place (division, ref fidelity) -----
__global__ void rowNormInplaceK(float* __restrict__ buf) {
    int wave = threadIdx.x >> 6, lane = threadIdx.x & 63;
    int row = blockIdx.x * 4 + wave;
    float* p = buf + (size_t)row * DD;
    float4 v0 = *(float4*)&p[lane * 8];
    float4 v1 = *(float4*)&p[lane * 8 + 4];
    float ss = v0.x*v0.x + v0.y*v0.y + v0.z*v0.z + v0.w*v0.w
             + v1.x*v1.x + v1.y*v1.y + v1.z*v1.z + v1.w*v1.w;
    ss = waveSum(ss);
    float nrm = fmaxf(sqrtf(ss), 1e-12f);
    v0.x /= nrm; v0.y /= nrm; v0.z /= nrm; v0.w /= nrm;
    v1.x /= nrm; v1.y /= nrm; v1.z /= nrm; v1.w /= nrm;
    *(float4*)&p[lane * 8] = v0;
    *(float4*)&p[lane * 8 + 4] = v1;
}

// ---------------- per-row norms of residual ----------------
__global__ void rowInvNormK(const float* __restrict__ resid,
                            float* __restrict__ rinv, float* __restrict__ rnrm) {
    int wave = threadIdx.x >> 6, lane = threadIdx.x & 63;
    int row = blockIdx.x * 4 + wave;
    const float* p = resid + (size_t)row * DD;
    float4 v0 = *(const float4*)&p[lane * 8];
    float4 v1 = *(const float4*)&p[lane * 8 + 4];
    float ss = v0.x*v0.x + v0.y*v0.y + v0.z*v0.z + v0.w*v0.w
             + v1.x*v1.x + v1.y*v1.y + v1.z*v1.z + v1.w*v1.w;
    ss = waveSum(ss);
    float nrm = fmaxf(sqrtf(ss), 1e-12f);
    if (lane == 0) { rinv[row] = 1.0f / nrm; rnrm[row] = nrm; }
}

// ---------------- fused sim GEMM + argmax ----------------
// 128 rows x 512 cols per block (c split in 8 chunks), BK=16, 8x8 thread tiles.
// LDS rows padded to 132 floats (bank rotation); B thread fragments split to
// tx*4 and 64+tx*4 so all LDS reads/writes are <=2-way (free) bank aliasing.
__global__ __launch_bounds__(256) void simArgmaxK(const float* __restrict__ resid,
                                                  const float* __restrict__ rinv,
                                                  const float* __restrict__ cbn,
                                                  float* __restrict__ pvals,
                                                  int* __restrict__ pidx) {
    __shared__ float As[16][132];
    __shared__ float Bs[16][132];
    int t = threadIdx.x;
    int tx = t & 15, ty = t >> 4;
    int rowBase = blockIdx.x * 128;
    int ch = blockIdx.y;               // which c chunk
    int cBase = ch * CCHUNK;
    int ml = t >> 2;                   // 0..63
    int kq = (t & 3) * 4;              // 0,4,8,12
    float s0 = rinv[rowBase + ml];
    float s1 = rinv[rowBase + ml + 64];
    float best[8]; int bidx[8];
#pragma unroll
    for (int i = 0; i < 8; ++i) { best[i] = -3e38f; bidx[i] = 0; }

    for (int ct = 0; ct < CCHUNK; ct += 128) {
        float acc[8][8] = {};
        for (int k0 = 0; k0 < DD; k0 += 16) {
            __syncthreads();
            {
                float4 av = *(const float4*)&resid[(size_t)(rowBase + ml) * DD + k0 + kq];
                As[kq+0][ml] = av.x * s0; As[kq+1][ml] = av.y * s0;
                As[kq+2][ml] = av.z * s0; As[kq+3][ml] = av.w * s0;
                float4 av2 = *(const float4*)&resid[(size_t)(rowBase + ml + 64) * DD + k0 + kq];
                As[kq+0][ml+64] = av2.x * s1; As[kq+1][ml+64] = av2.y * s1;
                As[kq+2][ml+64] = av2.z * s1; As[kq+3][ml+64] = av2.w * s1;
                float4 bv = *(const float4*)&cbn[(size_t)(cBase + ct + ml) * DD + k0 + kq];
                Bs[kq+0][ml] = bv.x; Bs[kq+1][ml] = bv.y;
                Bs[kq+2][ml] = bv.z; Bs[kq+3][ml] = bv.w;
                float4 bv2 = *(const float4*)&cbn[(size_t)(cBase + ct + ml + 64) * DD + k0 + kq];
                Bs[kq+0][ml+64] = bv2.x; Bs[kq+1][ml+64] = bv2.y;
                Bs[kq+2][ml+64] = bv2.z; Bs[kq+3][ml+64] = bv2.w;
            }
            __syncthreads();
#pragma unroll
            for (int kk = 0; kk < 16; ++kk) {
                float4 a0 = *(const float4*)&As[kk][ty * 8];
                float4 a1 = *(const float4*)&As[kk][ty * 8 + 4];
                float4 b0 = *(const float4*)&Bs[kk][tx * 4];
                float4 b1 = *(const float4*)&Bs[kk][64 + tx * 4];
                float a[8] = {a0.x,a0.y,a0.z,a0.w,a1.x,a1.y,a1.z,a1.w};
                float b[8] = {b0.x,b0.y,b0.z,b0.w,b1.x,b1.y,b1.z,b1.w};
#pragma unroll
                for (int i = 0; i < 8; ++i)
#pragma unroll
                    for (int j = 0; j < 8; ++j) acc[i][j] += a[i] * b[j];
            }
        }
        // per-row argmax over this 128-col tile (first-max tie-break).
        // thread col j: j<4 -> ct+tx*4+j ; j>=4 -> ct+64+tx*4+(j-4)  (ascending in j)
#pragma unroll
        for (int i = 0; i < 8; ++i) {
            float v = acc[i][0];
            int ci = cBase + ct + tx * 4;
#pragma unroll
            for (int j = 1; j < 8; ++j) {
                int cj = cBase + ct + (j < 4 ? tx * 4 + j : 64 + tx * 4 + (j - 4));
                if (acc[i][j] > v) { v = acc[i][j]; ci = cj; }
            }
#pragma unroll
            for (int m = 1; m < 16; m <<= 1) {
                float ov = __shfl_xor(v, m, 64);
                int oc = __shfl_xor(ci, m, 64);
                if (ov > v || (ov == v && oc < ci)) { v = ov; ci = oc; }
            }
            if (v > best[i] || (v == best[i] && ci < bidx[i])) { best[i] = v; bidx[i] = ci; }
        }
    }
    if (tx == 0) {
#pragma unroll
        for (int i = 0; i < 8; ++i) {
            int row = rowBase + ty * 8 + i;
            pvals[row * CSPLIT + ch] = best[i];
            pidx[row * CSPLIT + ch] = bidx[i];
        }
    }
}

// ---------------- finalize: merge chunks, rotation, residual/qout/loss --------
__global__ void finalizeK(float* __restrict__ resid,
                          const float* __restrict__ rnrm,
                          const float* __restrict__ cbn,
                          const float* __restrict__ pvals,
                          const int* __restrict__ pidx,
                          float* __restrict__ dout,
                          float* __restrict__ loss, int q) {
    int wave = threadIdx.x >> 6, lane = threadIdx.x & 63;
    int row = blockIdx.x * 4 + wave;
    float* xr = resid + (size_t)row * DD;
    float nrm = rnrm[row];
    float4 a0 = *(float4*)&xr[lane * 8];
    float4 a1 = *(float4*)&xr[lane * 8 + 4];
    float orig[8] = {a0.x,a0.y,a0.z,a0.w,a1.x,a1.y,a1.z,a1.w};
    float x[8];
#pragma unroll
    for (int j = 0; j < 8; ++j) x[j] = orig[j] / nrm;   // x_n, division per ref

    // merge CSPLIT partial maxima (chunks ascend in c; strict > keeps first max)
    float bv = pvals[row * CSPLIT];
    int idx = pidx[row * CSPLIT];
#pragma unroll
    for (int c = 1; c < CSPLIT; ++c) {
        float pv = pvals[row * CSPLIT + c];
        if (pv > bv) { bv = pv; idx = pidx[row * CSPLIT + c]; }
    }

    const float* qp = cbn + (size_t)idx * DD;
    float4 q0 = *(const float4*)&qp[lane * 8];
    float4 q1 = *(const float4*)&qp[lane * 8 + 4];
    float qv[8] = {q0.x,q0.y,q0.z,q0.w,q1.x,q1.y,q1.z,q1.w};

    float ns2 = 0.f, nt2 = 0.f, lrow = 0.f;
#pragma unroll
    for (int j = 0; j < 8; ++j) {
        ns2 += x[j] * x[j];
        nt2 += qv[j] * qv[j];
        float d = x[j] - qv[j];
        lrow += d * d;
    }
    ns2 = waveSum(ns2); nt2 = waveSum(nt2); lrow = waveSum(lrow);
    float ns = sqrtf(ns2), nt = sqrtf(nt2);

    float u[8], qn[8], w[8];
    float nw2 = 0.f;
#pragma unroll
    for (int j = 0; j < 8; ++j) {
        u[j] = x[j] / ns;
        qn[j] = qv[j] / nt;
        w[j] = u[j] + qn[j];
        nw2 += w[j] * w[j];
    }
    nw2 = waveSum(nw2);
    float nw = fmaxf(sqrtf(nw2), 1e-12f);
    float dew = 0.f, deu = 0.f;
#pragma unroll
    for (int j = 0; j < 8; ++j) {
        w[j] = w[j] / nw;
        dew += x[j] * w[j];
        deu += x[j] * u[j];
    }
    dew = waveSum(dew); deu = waveSum(deu);
    float scale = nt / ns;

    float r[8];
#pragma unroll
    for (int j = 0; j < 8; ++j)
        r[j] = (x[j] - 2.0f * dew * w[j] + 2.0f * deu * qn[j]) * scale;

    // residual -= r ; qout += r
    a0.x = orig[0]-r[0]; a0.y = orig[1]-r[1]; a0.z = orig[2]-r[2]; a0.w = orig[3]-r[3];
    a1.x = orig[4]-r[4]; a1.y = orig[5]-r[5]; a1.z = orig[6]-r[6]; a1.w = orig[7]-r[7];
    *(float4*)&xr[lane * 8] = a0;
    *(float4*)&xr[lane * 8 + 4] = a1;

    float* op = dout + (size_t)row * DD;
    float4 o0 = *(float4*)&op[lane * 8];
    float4 o1 = *(float4*)&op[lane * 8 + 4];
    o0.x += r[0]; o0.y += r[1]; o0.z += r[2]; o0.w += r[3];
    o1.x += r[4]; o1.y += r[5]; o1.z += r[6]; o1.w += r[7];
    *(float4*)&op[lane * 8] = o0;
    *(float4*)&op[lane * 8 + 4] = o1;

    if (lane == 0) {
        dout[IDX_OFF + row * 4 + q] = (float)idx;
        atomicAdd(loss + q, lrow * LOSS_COEF);
    }
}

__global__ void lossWriteK(const float* __restrict__ loss, float* __restrict__ dout) {
    if (threadIdx.x < QQ) dout[LOSS_OFF + threadIdx.x] = loss[threadIdx.x];
}

extern "C" void kernel_launch(void* const* d_in, const int* in_sizes, int n_in,
                              void* d_out, int out_size, void* d_ws, size_t ws_size,
                              hipStream_t stream) {
    const float* x = (const float*)d_in[0];
    const float* codebooks = (const float*)d_in[1];
    const float* weights = (const float*)d_in[2];
    float* dout = (float*)d_out;
    float* w = (float*)d_ws;

    float* resid = w + WS_RESID;
    float* cbn   = w + WS_CBN;
    float* rinv  = w + WS_RINV;
    float* rnrm  = w + WS_RNRM;
    float* pvals = w + WS_PVAL;
    int*   pidx  = (int*)(w + WS_PIDX);
    float* loss  = w + WS_LOSS;

    initK<<<4096, 256, 0, stream>>>(x, resid, dout, loss);

    for (int q = 0; q < QQ; ++q) {
        gemmCbK<<<dim3(CC / 64, DD / 64), 256, 0, stream>>>(
            codebooks + (size_t)q * CC * DD, weights + (size_t)q * DD * DD, cbn);
        rowNormInplaceK<<<CC / 4, 256, 0, stream>>>(cbn);
        rowInvNormK<<<RR / 4, 256, 0, stream>>>(resid, rinv, rnrm);
        simArgmaxK<<<dim3(RR / 128, CSPLIT), 256, 0, stream>>>(resid, rinv, cbn, pvals, pidx);
        finalizeK<<<RR / 4, 256, 0, stream>>>(resid, rnrm, cbn, pvals, pidx, dout, loss, q);
    }
    lossWriteK<<<1, 64, 0, stream>>>(loss, dout);
}